// Round 6
// baseline (1137.300 us; speedup 1.0000x reference)
//
#include <hip/hip_runtime.h>
#include <stdint.h>

// PoseGuidedMultipoleFusion — MI355X bf16 MFMA implementation.
// B=8, NQ=100, C=768, H0=64, NH=8 (d=96), NS=3, HID=3072.
// Workspace use ~294 MB.

typedef unsigned short u16;
typedef __attribute__((ext_vector_type(4))) float f32x4;
typedef __attribute__((ext_vector_type(8))) short s16x8;
typedef __attribute__((ext_vector_type(4))) short s16x4;

#define DEVI static __device__ __forceinline__

DEVI float bf2f(u16 u){ union { unsigned int ui; float f; } v; v.ui = ((unsigned int)u)<<16; return v.f; }
DEVI u16 f2bf(float f){ union { float f; unsigned int ui; } v; v.f = f;
  unsigned int r = v.ui + 0x7FFFu + ((v.ui>>16)&1u); return (u16)(r>>16); }
DEVI f32x4 mfma_bf16(s16x8 a, s16x8 b, f32x4 c){
  return __builtin_amdgcn_mfma_f32_16x16x32_bf16(a,b,c,0,0,0);
}
// async global->LDS, 16B per lane. LDS side must be linear (base + lane*16).
DEVI void gload_lds16(const void* g, void* l){
  __builtin_amdgcn_global_load_lds((const __attribute__((address_space(1))) void*)g,
                                   (__attribute__((address_space(3))) void*)l, 16, 0, 0);
}

// ---------------- small prep kernels ----------------

__global__ __launch_bounds__(64) void smax3_k(const float* __restrict__ sw, float* __restrict__ w3){
  if (threadIdx.x==0){
    float a=sw[0],b=sw[1],c=sw[2];
    float mx=fmaxf(a,fmaxf(b,c));
    float ea=__expf(a-mx), eb=__expf(b-mx), ec=__expf(c-mx);
    float inv=1.f/(ea+eb+ec);
    w3[0]=ea*inv; w3[1]=eb*inv; w3[2]=ec*inv;
  }
}

__global__ __launch_bounds__(256) void cvt_k(const float* __restrict__ in, u16* __restrict__ out, int n4){
  int i = blockIdx.x*256 + threadIdx.x;
  if (i>=n4) return;
  f32x4 v = *(const f32x4*)(in + (long)i*4);
  s16x4 o;
  o[0]=(short)f2bf(v[0]); o[1]=(short)f2bf(v[1]); o[2]=(short)f2bf(v[2]); o[3]=(short)f2bf(v[3]);
  *(s16x4*)(out + (long)i*4) = o;
}

// transpose f32 [z][R][C] -> bf16 [z][C][R]
__global__ __launch_bounds__(256) void tr_k(const float* __restrict__ in, u16* __restrict__ out, int R, int C){
  __shared__ float tile[32][33];
  long z = blockIdx.z;
  in  += z*(long)R*C;
  out += z*(long)R*C;
  int tx = threadIdx.x & 31, ty = threadIdx.x>>5;   // 32 x 8
  int r0 = blockIdx.y*32, c0 = blockIdx.x*32;
#pragma unroll
  for (int j=0;j<4;++j) tile[ty+j*8][tx] = in[(long)(r0+ty+j*8)*C + c0+tx];
  __syncthreads();
#pragma unroll
  for (int j=0;j<4;++j) out[(long)(c0+ty+j*8)*R + r0+tx] = f2bf(tile[tx][ty+j*8]);
}

// ds_w [2][O=768][I=768][dyx=4] f32  ->  wcv_t [2][4][O][I] bf16 (B' = W^T per shift)
__global__ __launch_bounds__(256) void convw_k(const float* __restrict__ dsw, u16* __restrict__ out){
  int i = blockIdx.x*256 + threadIdx.x;           // over 2*768*768
  f32x4 v = *(const f32x4*)(dsw + (long)i*4);
  int s = i/(768*768); int rem = i - s*768*768;
  int o = rem/768; int ii = rem - o*768;
#pragma unroll
  for (int dyx=0;dyx<4;++dyx)
    out[(((long)s*4+dyx)*768 + o)*768 + ii] = f2bf(v[dyx]);
}

// ---------------- LayerNorm over C=768 (bf16 in/out), one wave per row ----------------
__global__ __launch_bounds__(256) void ln_bf16_k(const u16* __restrict__ in, u16* __restrict__ out,
    const float* __restrict__ g, const float* __restrict__ bt, int nrows){
  int w = threadIdx.x>>6, lane = threadIdx.x&63;
  long row = (long)blockIdx.x*4 + w;
  if (row >= nrows) return;
  const u16* rp = in + row*768;
  s16x8 v8 = *(const s16x8*)(rp + lane*8);
  s16x4 v4 = *(const s16x4*)(rp + 512 + lane*4);
  float x[12];
#pragma unroll
  for (int i=0;i<8;++i) x[i]   = bf2f((u16)v8[i]);
#pragma unroll
  for (int i=0;i<4;++i) x[8+i] = bf2f((u16)v4[i]);
  float s=0.f,s2=0.f;
#pragma unroll
  for (int i=0;i<12;++i){ s += x[i]; s2 += x[i]*x[i]; }
  for (int m=1;m<64;m<<=1){ s += __shfl_xor(s,m); s2 += __shfl_xor(s2,m); }
  float mean = s*(1.f/768.f);
  float var  = s2*(1.f/768.f) - mean*mean;
  float rstd = rsqrtf(fmaxf(var,0.f)+1e-5f);
  u16* op = out + row*768;
  s16x8 o8; s16x4 o4;
#pragma unroll
  for (int i=0;i<8;++i){ int c = lane*8+i;     o8[i] = (short)f2bf((x[i]-mean)*rstd*g[c]+bt[c]); }
#pragma unroll
  for (int i=0;i<4;++i){ int c = 512+lane*4+i; o4[i] = (short)f2bf((x[8+i]-mean)*rstd*g[c]+bt[c]); }
  *(s16x8*)(op + lane*8) = o8;
  *(s16x4*)(op + 512 + lane*4) = o4;
}

// ---------------- keypoint distance bias ----------------
__global__ __launch_bounds__(256) void bias_k(const float* __restrict__ kpts, float* __restrict__ out,
    int HW, int log2W, float invWm1, float invHm1, float inv2s2){
  __shared__ float2 kp[17];
  int b = blockIdx.y;
  if (threadIdx.x < 17) kp[threadIdx.x] = ((const float2*)kpts)[b*17 + threadIdx.x];
  __syncthreads();
  int p = blockIdx.x*256 + threadIdx.x;
  int W = 1<<log2W;
  int y = p>>log2W, x = p&(W-1);
  float gx = x*invWm1, gy = y*invHm1;
  float m = 1e30f;
#pragma unroll 1
  for (int k=0;k<17;++k){
    float kx = fminf(fmaxf(kp[k].x,0.f),1.f) - gx;
    float ky = fminf(fmaxf(kp[k].y,0.f),1.f) - gy;
    m = fminf(m, kx*kx+ky*ky);
  }
  out[(long)b*HW + p] = fmaxf(-m*inv2s2, -10000.f);
}

// ---------------- generic bf16 MFMA GEMM ----------------
// C[M,N] = A[M,K] @ B'[N,K]^T (+bias). OUTM: 0 bf16, 1 f32, 2 f32 accumulate alpha, 3 bf16 transposed (V^T).
// QPAD: out row remap r -> (r/100)*128 + r%100.  CONV: A-row remap + 4 dyx shifts of B'.
// NOTE: A must be readable for ceil(M/128)*128 rows (pad buffers); epilogue guards row<M.
template<int OUTM, bool RELU, bool QPAD, bool CONV>
__global__ __launch_bounds__(256,2) void gemm_k(
    const u16* __restrict__ A, const u16* __restrict__ Bt,
    const float* __restrict__ bias, void* __restrict__ Cout,
    int M, int N, int K,
    const float* __restrict__ alpha_ptr, int accum_init,
    int Win, int HWin, int log2Wout, int log2HWout, int ldct)
{
  __shared__ u16 As[128*32];
  __shared__ u16 Bs[128*32];
  const int t = threadIdx.x, lane = t&63, w = t>>6;
  const int wr = w>>1, wc = w&1;
  const int m0 = blockIdx.x*128, n0 = blockIdx.y*128;
  f32x4 acc[4][4];
  const f32x4 fz = {0.f,0.f,0.f,0.f};
#pragma unroll
  for (int i=0;i<4;++i)
#pragma unroll
    for (int j=0;j<4;++j) acc[i][j] = fz;
  const int ndyx = CONV ? 4 : 1;
  for (int dyx=0; dyx<ndyx; ++dyx){
    const u16* Bp = CONV ? (Bt + (long)dyx*N*K) : Bt;
    const int dy = dyx>>1, dx = dyx&1;
    for (int k0=0; k0<K; k0+=32){
      __syncthreads();
#pragma unroll
      for (int p=0;p<2;++p){
        int f = p*256+t, r = f>>2, cv = f&3;
        int gm = m0 + r;
        long arow;
        if (CONV){
          int bb = gm >> log2HWout;
          int pp = gm & ((1<<log2HWout)-1);
          int yy = pp >> log2Wout, xx = pp & ((1<<log2Wout)-1);
          arow = (long)bb*HWin + (2*yy+dy)*Win + (2*xx+dx);
        } else arow = gm;
        gload_lds16(A + arow*(long)K + k0 + cv*8, &As[(long)f*8]);
      }
#pragma unroll
      for (int p=0;p<2;++p){
        int f = p*256+t, r = f>>2, cv = f&3;
        gload_lds16(Bp + (long)(n0+r)*K + k0 + cv*8, &Bs[(long)f*8]);
      }
      __syncthreads();
      s16x8 af[4], bf[4];
#pragma unroll
      for (int i=0;i<4;++i) af[i] = *(const s16x8*)&As[(wr*64+i*16+(lane&15))*32 + (lane>>4)*8];
#pragma unroll
      for (int j=0;j<4;++j) bf[j] = *(const s16x8*)&Bs[(wc*64+j*16+(lane&15))*32 + (lane>>4)*8];
#pragma unroll
      for (int i=0;i<4;++i)
#pragma unroll
        for (int j=0;j<4;++j)
          acc[i][j] = mfma_bf16(af[i], bf[j], acc[i][j]);
    }
  }
  // epilogue: C/D layout col=lane&15, row=(lane>>4)*4+r
  const int col16 = lane&15, g = lane>>4;
  float alpha = (OUTM==2) ? *alpha_ptr : 1.f;
#pragma unroll
  for (int i=0;i<4;++i){
    int rowbase = m0 + wr*64 + i*16 + g*4;
#pragma unroll
    for (int j=0;j<4;++j){
      int colg = n0 + wc*64 + j*16 + col16;
      float bv = bias ? bias[colg] : 0.f;
      f32x4 c = acc[i][j];
      if (OUTM==3){
        if (rowbase < M){
          int bb  = rowbase >> log2HWout;
          int pix = rowbase & ((1<<log2HWout)-1);
          s16x4 pk;
          pk[0]=(short)f2bf(c[0]+bv); pk[1]=(short)f2bf(c[1]+bv);
          pk[2]=(short)f2bf(c[2]+bv); pk[3]=(short)f2bf(c[3]+bv);
          *(s16x4*)((u16*)Cout + ((long)bb*768 + colg)*ldct + pix) = pk;
        }
      } else {
#pragma unroll
        for (int r=0;r<4;++r){
          int row = rowbase + r;
          if (row < M){
            float v = c[r] + bv;
            if (RELU) v = fmaxf(v, 0.f);
            if (OUTM==0){
              long orow = row;
              if (QPAD){ int bb = row/100; orow = bb*128 + (row - bb*100); }
              ((u16*)Cout)[orow*(long)N + colg] = f2bf(v);
            } else if (OUTM==1){
              ((float*)Cout)[(long)row*N + colg] = v;
            } else {
              float* p = (float*)Cout + (long)row*N + colg;
              *p = (accum_init ? 0.f : *p) + alpha*v;
            }
          }
        }
      }
    }
  }
}

// ---------------- flash attention, k-chunked ----------------
// Qp [B][128][768] bf16 (rows>=100 zero), Kb [B][HW][768] bf16, Vt [B][768][HW] bf16, biasb [B][HW] f32.
// Opart [nch][64][128][96] f32 (unnormalized), mpart/lpart [nch][64][128].
__global__ __launch_bounds__(256,2) void attn_fwd_k(
    const u16* __restrict__ Qp, const u16* __restrict__ Kb,
    const u16* __restrict__ Vt, const float* __restrict__ biasb,
    float* __restrict__ Opart, float* __restrict__ mpart, float* __restrict__ lpart,
    int HW, int ntiles)
{
  __shared__ u16 Ps[4*32*64];   // per-wave 32x64 bf16, XOR-swizzled
  const int t = threadIdx.x, lane = t&63, w = t>>6;
  const int col = lane&15, g = lane>>4;
  const int bh = blockIdx.x, b = bh>>3, h = bh&7, ch = blockIdx.y;
  const int kvbase = ch*ntiles*64;
  const int qrow = w*32;
  const u16* Qbase = Qp + (long)b*128*768 + h*96;
  const u16* Kbase = Kb + (long)b*HW*768 + h*96;
  const u16* Vbase = Vt + ((long)b*768 + h*96)*HW;
  const float* bb  = biasb + (long)b*HW;
  const float scale = 0.10206207261596575f;  // 96^-0.5

  s16x8 qf[2][3];
#pragma unroll
  for (int qi=0;qi<2;++qi)
#pragma unroll
    for (int kf=0;kf<3;++kf)
      qf[qi][kf] = *(const s16x8*)(Qbase + (long)(qrow+qi*16+col)*768 + kf*32 + g*8);

  const f32x4 fz = {0.f,0.f,0.f,0.f};
  f32x4 of[2][6];
#pragma unroll
  for (int qi=0;qi<2;++qi)
#pragma unroll
    for (int nf=0;nf<6;++nf) of[qi][nf] = fz;
  float mrow[2][4], lrow[2][4];
#pragma unroll
  for (int qi=0;qi<2;++qi)
#pragma unroll
    for (int r=0;r<4;++r){ mrow[qi][r] = -1e30f; lrow[qi][r] = 0.f; }

  for (int ti=0; ti<ntiles; ++ti){
    const int kv0 = kvbase + ti*64;
    s16x8 kfr[4][3];
#pragma unroll
    for (int cf=0;cf<4;++cf)
#pragma unroll
      for (int kf=0;kf<3;++kf)
        kfr[cf][kf] = *(const s16x8*)(Kbase + (long)(kv0+cf*16+col)*768 + kf*32 + g*8);
    f32x4 sc[2][4];
#pragma unroll
    for (int qi=0;qi<2;++qi)
#pragma unroll
      for (int cf=0;cf<4;++cf) sc[qi][cf] = fz;
#pragma unroll
    for (int kf=0;kf<3;++kf)
#pragma unroll
      for (int qi=0;qi<2;++qi)
#pragma unroll
        for (int cf=0;cf<4;++cf)
          sc[qi][cf] = mfma_bf16(qf[qi][kf], kfr[cf][kf], sc[qi][cf]);
    float bv[4];
#pragma unroll
    for (int cf=0;cf<4;++cf) bv[cf] = bb[kv0+cf*16+col];

#pragma unroll
    for (int qi=0;qi<2;++qi){
      f32x4 sp[4];
#pragma unroll
      for (int cf=0;cf<4;++cf)
#pragma unroll
        for (int r=0;r<4;++r) sp[cf][r] = sc[qi][cf][r]*scale + bv[cf];
      f32x4 mx = sp[0];
#pragma unroll
      for (int cf=1;cf<4;++cf)
#pragma unroll
        for (int r=0;r<4;++r) mx[r] = fmaxf(mx[r], sp[cf][r]);
      for (int mm=1;mm<16;mm<<=1){
#pragma unroll
        for (int r=0;r<4;++r) mx[r] = fmaxf(mx[r], __shfl_xor(mx[r], mm));
      }
      float sf[4], mn[4];
#pragma unroll
      for (int r=0;r<4;++r){
        mn[r] = fmaxf(mrow[qi][r], mx[r]);
        sf[r] = __expf(mrow[qi][r]-mn[r]);
        mrow[qi][r] = mn[r];
      }
      f32x4 psum = fz;
#pragma unroll
      for (int cf=0;cf<4;++cf)
#pragma unroll
        for (int r=0;r<4;++r){ float p = __expf(sp[cf][r]-mn[r]); sp[cf][r]=p; psum[r]+=p; }
      for (int mm=1;mm<16;mm<<=1){
#pragma unroll
        for (int r=0;r<4;++r) psum[r] += __shfl_xor(psum[r], mm);
      }
#pragma unroll
      for (int r=0;r<4;++r) lrow[qi][r] = lrow[qi][r]*sf[r] + psum[r];
#pragma unroll
      for (int nf=0;nf<6;++nf)
#pragma unroll
        for (int r=0;r<4;++r) of[qi][nf][r] *= sf[r];
      // store P tile (bf16) to swizzled LDS
#pragma unroll
      for (int cf=0;cf<4;++cf)
#pragma unroll
        for (int r=0;r<4;++r){
          int lr = qi*16 + g*4 + r;
          int cc = cf*16 + col;
          int byteoff = (qrow + lr)*128 + ((cc*2) ^ ((lr&7)<<4));
          *(u16*)((char*)Ps + byteoff) = f2bf(sp[cf][r]);
        }
    }
    // PV: O += P @ V  (all within the same wave; compiler orders LDS ops)
#pragma unroll
    for (int k2=0;k2<2;++k2){
      s16x8 pa[2];
#pragma unroll
      for (int qi=0;qi<2;++qi){
        int lr = qi*16 + col;
        int byteoff = (qrow+lr)*128 + ((k2*64 + g*16) ^ ((lr&7)<<4));
        pa[qi] = *(const s16x8*)((const char*)Ps + byteoff);
      }
#pragma unroll
      for (int nf=0;nf<6;++nf){
        s16x8 vbf = *(const s16x8*)(Vbase + (long)(nf*16+col)*HW + kv0 + k2*32 + g*8);
#pragma unroll
        for (int qi=0;qi<2;++qi)
          of[qi][nf] = mfma_bf16(pa[qi], vbf, of[qi][nf]);
      }
    }
  }
  long obase = ((long)ch*64 + bh)*128;
#pragma unroll
  for (int qi=0;qi<2;++qi)
#pragma unroll
    for (int nf=0;nf<6;++nf)
#pragma unroll
      for (int r=0;r<4;++r)
        Opart[(obase + qrow + qi*16 + g*4 + r)*96L + nf*16 + col] = of[qi][nf][r];
  if (col==0){
#pragma unroll
    for (int qi=0;qi<2;++qi)
#pragma unroll
      for (int r=0;r<4;++r){
        int row = qrow + qi*16 + g*4 + r;
        mpart[obase+row] = mrow[qi][r];
        lpart[obase+row] = lrow[qi][r];
      }
  }
}

__global__ __launch_bounds__(128) void attn_comb_k(const float* __restrict__ Opart,
    const float* __restrict__ mpart, const float* __restrict__ lpart,
    u16* __restrict__ out, int nch){
  int bh = blockIdx.x, q = blockIdx.y, d = threadIdx.x;
  int b = bh>>3, h = bh&7;
  float M = -1e30f;
  for (int c=0;c<nch;++c) M = fmaxf(M, mpart[((long)c*64+bh)*128+q]);
  float L = 0.f, o = 0.f;
  for (int c=0;c<nch;++c){
    long base = ((long)c*64+bh)*128+q;
    float e = __expf(mpart[base]-M);
    L += lpart[base]*e;
    if (d<96) o += Opart[base*96+d]*e;
  }
  if (d<96) out[((long)(b*100+q))*768 + h*96 + d] = f2bf(o/L);
}

// ---------------- residual + LN kernels (f32, wave per row) ----------------
__global__ __launch_bounds__(256) void postattn_k(const float* __restrict__ q,
    const float* __restrict__ fus, const float* __restrict__ g, const float* __restrict__ bt,
    float* __restrict__ x1f, u16* __restrict__ x1b){
  int w = threadIdx.x>>6, lane = threadIdx.x&63;
  long row = (long)blockIdx.x*4 + w;
  const f32x4* qp = (const f32x4*)(q   + row*768);
  const f32x4* fp = (const f32x4*)(fus + row*768);
  f32x4 xv[3];
  float s=0.f,s2=0.f;
#pragma unroll
  for (int p=0;p<3;++p){
    f32x4 a = qp[p*64+lane], c = fp[p*64+lane];
    xv[p] = a + c;
#pragma unroll
    for (int r=0;r<4;++r){ s += xv[p][r]; s2 += xv[p][r]*xv[p][r]; }
  }
  for (int m=1;m<64;m<<=1){ s += __shfl_xor(s,m); s2 += __shfl_xor(s2,m); }
  float mean = s*(1.f/768.f);
  float var  = s2*(1.f/768.f) - mean*mean;
  float rstd = rsqrtf(fmaxf(var,0.f)+1e-5f);
#pragma unroll
  for (int p=0;p<3;++p){
    int c0 = (p*64+lane)*4;
    f32x4 o; s16x4 ob;
#pragma unroll
    for (int r=0;r<4;++r){ o[r] = (xv[p][r]-mean)*rstd*g[c0+r]+bt[c0+r]; ob[r]=(short)f2bf(o[r]); }
    *(f32x4*)(x1f + row*768 + c0) = o;
    *(s16x4*)(x1b + row*768 + c0) = ob;
  }
}

__global__ __launch_bounds__(256) void final_k(const float* __restrict__ x1f,
    const float* __restrict__ yb, const float* __restrict__ g, const float* __restrict__ bt,
    float* __restrict__ out){
  int w = threadIdx.x>>6, lane = threadIdx.x&63;
  long row = (long)blockIdx.x*4 + w;
  const f32x4* xp = (const f32x4*)(x1f + row*768);
  const f32x4* yp = (const f32x4*)(yb  + row*768);
  f32x4 xv[3];
  float s=0.f,s2=0.f;
#pragma unroll
  for (int p=0;p<3;++p){
    f32x4 a = xp[p*64+lane], c = yp[p*64+lane];
    xv[p] = a + c;
#pragma unroll
    for (int r=0;r<4;++r){ s += xv[p][r]; s2 += xv[p][r]*xv[p][r]; }
  }
  for (int m=1;m<64;m<<=1){ s += __shfl_xor(s,m); s2 += __shfl_xor(s2,m); }
  float mean = s*(1.f/768.f);
  float var  = s2*(1.f/768.f) - mean*mean;
  float rstd = rsqrtf(fmaxf(var,0.f)+1e-5f);
#pragma unroll
  for (int p=0;p<3;++p){
    int c0 = (p*64+lane)*4;
    f32x4 o;
#pragma unroll
    for (int r=0;r<4;++r) o[r] = (xv[p][r]-mean)*rstd*g[c0+r]+bt[c0+r];
    *(f32x4*)(out + row*768 + c0) = o;
  }
}

// ---------------- launcher ----------------
extern "C" void kernel_launch(void* const* d_in, const int* in_sizes, int n_in,
                              void* d_out, int out_size, void* d_ws, size_t ws_size,
                              hipStream_t stream)
{
  (void)in_sizes; (void)n_in; (void)out_size; (void)ws_size;
  const float* query = (const float*)d_in[0];
  const float* imgf  = (const float*)d_in[1];
  const float* kpts  = (const float*)d_in[2];
  const float* nfg   = (const float*)d_in[3];
  const float* nfb   = (const float*)d_in[4];
  const float* dsw   = (const float*)d_in[5];
  const float* dsb   = (const float*)d_in[6];
  const float* qw    = (const float*)d_in[7];
  const float* qbv   = (const float*)d_in[8];
  const float* kw    = (const float*)d_in[9];
  const float* kbv   = (const float*)d_in[10];
  const float* vw    = (const float*)d_in[11];
  const float* vbv   = (const float*)d_in[12];
  const float* ow    = (const float*)d_in[13];
  const float* obv   = (const float*)d_in[14];
  const float* sw    = (const float*)d_in[15];
  const float* nag   = (const float*)d_in[16];
  const float* nab   = (const float*)d_in[17];
  const float* fw1   = (const float*)d_in[18];
  const float* fb1   = (const float*)d_in[19];
  const float* fw2   = (const float*)d_in[20];
  const float* fb2   = (const float*)d_in[21];
  const float* ngg   = (const float*)d_in[22];
  const float* ngb   = (const float*)d_in[23];
  float* out = (float*)d_out;

  char* ws = (char*)d_ws;
  size_t off = 0;
  auto carve = [&](size_t bytes)->char*{
    off = (off + 255) & ~(size_t)255;
    char* p = ws + off; off += bytes; return p;
  };
  float* w3     = (float*)carve(16);
  u16* wq_t     = (u16*)carve(3UL*768*768*2);
  u16* wk_t     = (u16*)carve(3UL*768*768*2);
  u16* wv_t     = (u16*)carve(3UL*768*768*2);
  u16* wo_t     = (u16*)carve(3UL*768*768*2);
  u16* wf1_t    = (u16*)carve(3072UL*768*2);
  u16* wf2_t    = (u16*)carve(768UL*3072*2);
  u16* wcv_t    = (u16*)carve(2UL*4*768*768*2);
  u16* qbf      = (u16*)carve(896UL*768*2);   // padded to 896 rows (A of M=800 GEMM)
  u16* Qpad     = (u16*)carve(8UL*128*768*2);
  u16* curr0    = (u16*)carve(8UL*4096*768*2);
  u16* curr1    = (u16*)carve(8UL*1024*768*2);
  u16* curr2    = (u16*)carve(8UL*256*768*2);
  u16* feat     = (u16*)carve(8UL*4096*768*2);
  u16* Kb       = (u16*)carve(8UL*4096*768*2);
  u16* Vt       = (u16*)carve(8UL*768*4096*2);
  float* biasb  = (float*)carve(8UL*4096*4);
  float* Opart  = (float*)carve(8UL*64*128*96*4);
  float* mpart  = (float*)carve(8UL*64*128*4);
  float* lpart  = (float*)carve(8UL*64*128*4);
  u16* attnO    = (u16*)carve(896UL*768*2);   // padded
  float* fusedb = (float*)carve(800UL*768*4);
  float* x1f    = (float*)carve(800UL*768*4);
  u16* x1b      = (u16*)carve(896UL*768*2);   // padded
  u16* hb       = (u16*)carve(896UL*3072*2);  // padded
  float* yb     = (float*)carve(800UL*768*4);

  hipMemsetAsync(Qpad, 0, 8UL*128*768*2, stream);
  smax3_k<<<1,64,0,stream>>>(sw, w3);
  cvt_k<<<600,256,0,stream>>>(query, qbf, 153600);
  tr_k<<<dim3(24,24,3),256,0,stream>>>(qw, wq_t, 768, 768);
  tr_k<<<dim3(24,24,3),256,0,stream>>>(kw, wk_t, 768, 768);
  tr_k<<<dim3(24,24,3),256,0,stream>>>(vw, wv_t, 768, 768);
  tr_k<<<dim3(24,24,3),256,0,stream>>>(ow, wo_t, 768, 768);
  tr_k<<<dim3(96,24,1),256,0,stream>>>(fw1, wf1_t, 768, 3072);
  tr_k<<<dim3(24,96,1),256,0,stream>>>(fw2, wf2_t, 3072, 768);
  convw_k<<<4608,256,0,stream>>>(dsw, wcv_t);
  tr_k<<<dim3(128,24,8),256,0,stream>>>(imgf, curr0, 768, 4096);

  const int HWs[3]    = {4096,1024,256};
  const int log2Ws[3] = {6,5,4};
  const int chunks[3] = {8,4,2};
  const float sig[3]  = {0.05f,0.15f,0.3f};
  u16* currp[3] = {curr0, curr1, curr2};

  for (int s=0;s<3;++s){
    int HW = HWs[s], W = 1<<log2Ws[s];
    int M = 8*HW;
    if (s>0){
      int HWin = HWs[s-1], Win = 1<<log2Ws[s-1];
      gemm_k<0,false,false,true><<<dim3(M/128,6),256,0,stream>>>(
        currp[s-1], wcv_t + (long)(s-1)*4*768*768, dsb + (s-1)*768, currp[s],
        M, 768, 768, nullptr, 0,
        Win, HWin, log2Ws[s], 2*log2Ws[s], 0);
    }
    ln_bf16_k<<<M/4,256,0,stream>>>(currp[s], feat, nfg, nfb, M);
    gemm_k<0,false,false,false><<<dim3(M/128,6),256,0,stream>>>(
      feat, wk_t + (long)s*768*768, kbv + s*768, Kb, M, 768, 768,
      nullptr, 0, 0,0,0,0,0);
    gemm_k<3,false,false,false><<<dim3(M/128,6),256,0,stream>>>(
      feat, wv_t + (long)s*768*768, vbv + s*768, Vt, M, 768, 768,
      nullptr, 0, 0,0,0, 2*log2Ws[s], HW);
    gemm_k<0,false,true,false><<<dim3(7,6),256,0,stream>>>(
      qbf, wq_t + (long)s*768*768, qbv + s*768, Qpad, 800, 768, 768,
      nullptr, 0, 0,0,0,0,0);
    float inv2s2 = 1.f/(2.f*sig[s]*sig[s]);
    float invWm1 = 1.f/(float)(W-1);
    bias_k<<<dim3(HW/256,8),256,0,stream>>>(kpts, biasb, HW, log2Ws[s], invWm1, invWm1, inv2s2);
    attn_fwd_k<<<dim3(64,chunks[s]),256,0,stream>>>(
      Qpad, Kb, Vt, biasb, Opart, mpart, lpart, HW, (HW/64)/chunks[s]);
    attn_comb_k<<<dim3(64,100),128,0,stream>>>(Opart, mpart, lpart, attnO, chunks[s]);
    gemm_k<2,false,false,false><<<dim3(7,6),256,0,stream>>>(
      attnO, wo_t + (long)s*768*768, obv + s*768, fusedb, 800, 768, 768,
      w3+s, (s==0)?1:0, 0,0,0,0,0);
  }

  postattn_k<<<200,256,0,stream>>>(query, fusedb, nag, nab, x1f, x1b);
  gemm_k<0,true,false,false><<<dim3(7,24),256,0,stream>>>(
    x1b, wf1_t, fb1, hb, 800, 3072, 768, nullptr, 0, 0,0,0,0,0);
  gemm_k<1,false,false,false><<<dim3(7,6),256,0,stream>>>(
    hb, wf2_t, fb2, yb, 800, 768, 3072, nullptr, 0, 0,0,0,0,0);
  final_k<<<200,256,0,stream>>>(x1f, yb, ngg, ngb, out);
}

// Round 7
// 1118.946 us; speedup vs baseline: 1.0164x; 1.0164x over previous
//
#include <hip/hip_runtime.h>
#include <stdint.h>

// PoseGuidedMultipoleFusion — MI355X bf16 MFMA implementation.
// B=8, NQ=100, C=768, H0=64, NH=8 (d=96), NS=3, HID=3072.
// R6: GEMM LDS XOR-swizzle (pre-swizzled gload source + swizzled read) to kill
//     the 8-way bank conflict (4.7M/dispatch @ R6 profile); launch_bounds(256,3).

typedef unsigned short u16;
typedef __attribute__((ext_vector_type(4))) float f32x4;
typedef __attribute__((ext_vector_type(8))) short s16x8;
typedef __attribute__((ext_vector_type(4))) short s16x4;

#define DEVI static __device__ __forceinline__

DEVI float bf2f(u16 u){ union { unsigned int ui; float f; } v; v.ui = ((unsigned int)u)<<16; return v.f; }
DEVI u16 f2bf(float f){ union { float f; unsigned int ui; } v; v.f = f;
  unsigned int r = v.ui + 0x7FFFu + ((v.ui>>16)&1u); return (u16)(r>>16); }
DEVI f32x4 mfma_bf16(s16x8 a, s16x8 b, f32x4 c){
  return __builtin_amdgcn_mfma_f32_16x16x32_bf16(a,b,c,0,0,0);
}
// async global->LDS, 16B per lane. LDS side must be linear (base + lane*16).
DEVI void gload_lds16(const void* g, void* l){
  __builtin_amdgcn_global_load_lds((const __attribute__((address_space(1))) void*)g,
                                   (__attribute__((address_space(3))) void*)l, 16, 0, 0);
}

// ---------------- small prep kernels ----------------

__global__ __launch_bounds__(64) void smax3_k(const float* __restrict__ sw, float* __restrict__ w3){
  if (threadIdx.x==0){
    float a=sw[0],b=sw[1],c=sw[2];
    float mx=fmaxf(a,fmaxf(b,c));
    float ea=__expf(a-mx), eb=__expf(b-mx), ec=__expf(c-mx);
    float inv=1.f/(ea+eb+ec);
    w3[0]=ea*inv; w3[1]=eb*inv; w3[2]=ec*inv;
  }
}

__global__ __launch_bounds__(256) void cvt_k(const float* __restrict__ in, u16* __restrict__ out, int n4){
  int i = blockIdx.x*256 + threadIdx.x;
  if (i>=n4) return;
  f32x4 v = *(const f32x4*)(in + (long)i*4);
  s16x4 o;
  o[0]=(short)f2bf(v[0]); o[1]=(short)f2bf(v[1]); o[2]=(short)f2bf(v[2]); o[3]=(short)f2bf(v[3]);
  *(s16x4*)(out + (long)i*4) = o;
}

// transpose f32 [z][R][C] -> bf16 [z][C][R]
__global__ __launch_bounds__(256) void tr_k(const float* __restrict__ in, u16* __restrict__ out, int R, int C){
  __shared__ float tile[32][33];
  long z = blockIdx.z;
  in  += z*(long)R*C;
  out += z*(long)R*C;
  int tx = threadIdx.x & 31, ty = threadIdx.x>>5;   // 32 x 8
  int r0 = blockIdx.y*32, c0 = blockIdx.x*32;
#pragma unroll
  for (int j=0;j<4;++j) tile[ty+j*8][tx] = in[(long)(r0+ty+j*8)*C + c0+tx];
  __syncthreads();
#pragma unroll
  for (int j=0;j<4;++j) out[(long)(c0+ty+j*8)*R + r0+tx] = f2bf(tile[tx][ty+j*8]);
}

// ds_w [2][O=768][I=768][dyx=4] f32  ->  wcv_t [2][4][O][I] bf16 (B' = W^T per shift)
__global__ __launch_bounds__(256) void convw_k(const float* __restrict__ dsw, u16* __restrict__ out){
  int i = blockIdx.x*256 + threadIdx.x;           // over 2*768*768
  f32x4 v = *(const f32x4*)(dsw + (long)i*4);
  int s = i/(768*768); int rem = i - s*768*768;
  int o = rem/768; int ii = rem - o*768;
#pragma unroll
  for (int dyx=0;dyx<4;++dyx)
    out[(((long)s*4+dyx)*768 + o)*768 + ii] = f2bf(v[dyx]);
}

// ---------------- LayerNorm over C=768 (bf16 in/out), one wave per row ----------------
__global__ __launch_bounds__(256) void ln_bf16_k(const u16* __restrict__ in, u16* __restrict__ out,
    const float* __restrict__ g, const float* __restrict__ bt, int nrows){
  int w = threadIdx.x>>6, lane = threadIdx.x&63;
  long row = (long)blockIdx.x*4 + w;
  if (row >= nrows) return;
  const u16* rp = in + row*768;
  s16x8 v8 = *(const s16x8*)(rp + lane*8);
  s16x4 v4 = *(const s16x4*)(rp + 512 + lane*4);
  float x[12];
#pragma unroll
  for (int i=0;i<8;++i) x[i]   = bf2f((u16)v8[i]);
#pragma unroll
  for (int i=0;i<4;++i) x[8+i] = bf2f((u16)v4[i]);
  float s=0.f,s2=0.f;
#pragma unroll
  for (int i=0;i<12;++i){ s += x[i]; s2 += x[i]*x[i]; }
  for (int m=1;m<64;m<<=1){ s += __shfl_xor(s,m); s2 += __shfl_xor(s2,m); }
  float mean = s*(1.f/768.f);
  float var  = s2*(1.f/768.f) - mean*mean;
  float rstd = rsqrtf(fmaxf(var,0.f)+1e-5f);
  u16* op = out + row*768;
  s16x8 o8; s16x4 o4;
#pragma unroll
  for (int i=0;i<8;++i){ int c = lane*8+i;     o8[i] = (short)f2bf((x[i]-mean)*rstd*g[c]+bt[c]); }
#pragma unroll
  for (int i=0;i<4;++i){ int c = 512+lane*4+i; o4[i] = (short)f2bf((x[8+i]-mean)*rstd*g[c]+bt[c]); }
  *(s16x8*)(op + lane*8) = o8;
  *(s16x4*)(op + 512 + lane*4) = o4;
}

// ---------------- keypoint distance bias ----------------
__global__ __launch_bounds__(256) void bias_k(const float* __restrict__ kpts, float* __restrict__ out,
    int HW, int log2W, float invWm1, float invHm1, float inv2s2){
  __shared__ float2 kp[17];
  int b = blockIdx.y;
  if (threadIdx.x < 17) kp[threadIdx.x] = ((const float2*)kpts)[b*17 + threadIdx.x];
  __syncthreads();
  int p = blockIdx.x*256 + threadIdx.x;
  int W = 1<<log2W;
  int y = p>>log2W, x = p&(W-1);
  float gx = x*invWm1, gy = y*invHm1;
  float m = 1e30f;
#pragma unroll 1
  for (int k=0;k<17;++k){
    float kx = fminf(fmaxf(kp[k].x,0.f),1.f) - gx;
    float ky = fminf(fmaxf(kp[k].y,0.f),1.f) - gy;
    m = fminf(m, kx*kx+ky*ky);
  }
  out[(long)b*HW + p] = fmaxf(-m*inv2s2, -10000.f);
}

// ---------------- generic bf16 MFMA GEMM ----------------
// C[M,N] = A[M,K] @ B'[N,K]^T (+bias). OUTM: 0 bf16, 1 f32, 2 f32 accumulate alpha, 3 bf16 transposed (V^T).
// QPAD: out row remap r -> (r/100)*128 + r%100.  CONV: A-row remap + 4 dyx shifts of B'.
// NOTE: A must be readable for ceil(M/128)*128 rows (pad buffers); epilogue guards row<M.
// LDS swizzle: physical 16B-block (r,cv) holds logical block cv^((r>>1)&3); applied on the
// GLOBAL source (gload_lds dest must stay linear, rule #21) and inverted on the ds_read.
// Bank math: read bank-start = (16*row + 4*(g^((row>>1)&3))) mod 32 -> 8 starts x 2 lanes = 2-way (free).
template<int OUTM, bool RELU, bool QPAD, bool CONV>
__global__ __launch_bounds__(256,3) void gemm_k(
    const u16* __restrict__ A, const u16* __restrict__ Bt,
    const float* __restrict__ bias, void* __restrict__ Cout,
    int M, int N, int K,
    const float* __restrict__ alpha_ptr, int accum_init,
    int Win, int HWin, int log2Wout, int log2HWout, int ldct)
{
  __shared__ u16 As[128*32];
  __shared__ u16 Bs[128*32];
  const int t = threadIdx.x, lane = t&63, w = t>>6;
  const int wr = w>>1, wc = w&1;
  const int m0 = blockIdx.x*128, n0 = blockIdx.y*128;
  f32x4 acc[4][4];
  const f32x4 fz = {0.f,0.f,0.f,0.f};
#pragma unroll
  for (int i=0;i<4;++i)
#pragma unroll
    for (int j=0;j<4;++j) acc[i][j] = fz;
  const int ndyx = CONV ? 4 : 1;
  for (int dyx=0; dyx<ndyx; ++dyx){
    const u16* Bp = CONV ? (Bt + (long)dyx*N*K) : Bt;
    const int dy = dyx>>1, dx = dyx&1;
    for (int k0=0; k0<K; k0+=32){
      __syncthreads();
#pragma unroll
      for (int p=0;p<2;++p){
        int f = p*256+t, r = f>>2, cv = f&3;
        int cvs = cv ^ ((r>>1)&3);          // pre-swizzled global k-block
        int gm = m0 + r;
        long arow;
        if (CONV){
          int bb = gm >> log2HWout;
          int pp = gm & ((1<<log2HWout)-1);
          int yy = pp >> log2Wout, xx = pp & ((1<<log2Wout)-1);
          arow = (long)bb*HWin + (2*yy+dy)*Win + (2*xx+dx);
        } else arow = gm;
        gload_lds16(A + arow*(long)K + k0 + cvs*8, &As[(long)f*8]);
      }
#pragma unroll
      for (int p=0;p<2;++p){
        int f = p*256+t, r = f>>2, cv = f&3;
        int cvs = cv ^ ((r>>1)&3);
        gload_lds16(Bp + (long)(n0+r)*K + k0 + cvs*8, &Bs[(long)f*8]);
      }
      __syncthreads();
      const int g = lane>>4, l16 = lane&15;
      s16x8 af[4], bf[4];
#pragma unroll
      for (int i=0;i<4;++i){
        int row = wr*64 + i*16 + l16;
        af[i] = *(const s16x8*)&As[row*32 + ((g ^ ((row>>1)&3))*8)];
      }
#pragma unroll
      for (int j=0;j<4;++j){
        int row = wc*64 + j*16 + l16;
        bf[j] = *(const s16x8*)&Bs[row*32 + ((g ^ ((row>>1)&3))*8)];
      }
#pragma unroll
      for (int i=0;i<4;++i)
#pragma unroll
        for (int j=0;j<4;++j)
          acc[i][j] = mfma_bf16(af[i], bf[j], acc[i][j]);
    }
  }
  // epilogue: C/D layout col=lane&15, row=(lane>>4)*4+r
  const int col16 = lane&15, g = lane>>4;
  float alpha = (OUTM==2) ? *alpha_ptr : 1.f;
#pragma unroll
  for (int i=0;i<4;++i){
    int rowbase = m0 + wr*64 + i*16 + g*4;
#pragma unroll
    for (int j=0;j<4;++j){
      int colg = n0 + wc*64 + j*16 + col16;
      float bv = bias ? bias[colg] : 0.f;
      f32x4 c = acc[i][j];
      if (OUTM==3){
        if (rowbase < M){
          int bb  = rowbase >> log2HWout;
          int pix = rowbase & ((1<<log2HWout)-1);
          s16x4 pk;
          pk[0]=(short)f2bf(c[0]+bv); pk[1]=(short)f2bf(c[1]+bv);
          pk[2]=(short)f2bf(c[2]+bv); pk[3]=(short)f2bf(c[3]+bv);
          *(s16x4*)((u16*)Cout + ((long)bb*768 + colg)*ldct + pix) = pk;
        }
      } else {
#pragma unroll
        for (int r=0;r<4;++r){
          int row = rowbase + r;
          if (row < M){
            float v = c[r] + bv;
            if (RELU) v = fmaxf(v, 0.f);
            if (OUTM==0){
              long orow = row;
              if (QPAD){ int bb = row/100; orow = bb*128 + (row - bb*100); }
              ((u16*)Cout)[orow*(long)N + colg] = f2bf(v);
            } else if (OUTM==1){
              ((float*)Cout)[(long)row*N + colg] = v;
            } else {
              float* p = (float*)Cout + (long)row*N + colg;
              *p = (accum_init ? 0.f : *p) + alpha*v;
            }
          }
        }
      }
    }
  }
}

// ---------------- flash attention, k-chunked ----------------
// Qp [B][128][768] bf16 (rows>=100 zero), Kb [B][HW][768] bf16, Vt [B][768][HW] bf16, biasb [B][HW] f32.
// Opart [nch][64][128][96] f32 (unnormalized), mpart/lpart [nch][64][128].
__global__ __launch_bounds__(256,2) void attn_fwd_k(
    const u16* __restrict__ Qp, const u16* __restrict__ Kb,
    const u16* __restrict__ Vt, const float* __restrict__ biasb,
    float* __restrict__ Opart, float* __restrict__ mpart, float* __restrict__ lpart,
    int HW, int ntiles)
{
  __shared__ u16 Ps[4*32*64];   // per-wave 32x64 bf16, XOR-swizzled
  const int t = threadIdx.x, lane = t&63, w = t>>6;
  const int col = lane&15, g = lane>>4;
  const int bh = blockIdx.x, b = bh>>3, h = bh&7, ch = blockIdx.y;
  const int kvbase = ch*ntiles*64;
  const int qrow = w*32;
  const u16* Qbase = Qp + (long)b*128*768 + h*96;
  const u16* Kbase = Kb + (long)b*HW*768 + h*96;
  const u16* Vbase = Vt + ((long)b*768 + h*96)*HW;
  const float* bb  = biasb + (long)b*HW;
  const float scale = 0.10206207261596575f;  // 96^-0.5

  s16x8 qf[2][3];
#pragma unroll
  for (int qi=0;qi<2;++qi)
#pragma unroll
    for (int kf=0;kf<3;++kf)
      qf[qi][kf] = *(const s16x8*)(Qbase + (long)(qrow+qi*16+col)*768 + kf*32 + g*8);

  const f32x4 fz = {0.f,0.f,0.f,0.f};
  f32x4 of[2][6];
#pragma unroll
  for (int qi=0;qi<2;++qi)
#pragma unroll
    for (int nf=0;nf<6;++nf) of[qi][nf] = fz;
  float mrow[2][4], lrow[2][4];
#pragma unroll
  for (int qi=0;qi<2;++qi)
#pragma unroll
    for (int r=0;r<4;++r){ mrow[qi][r] = -1e30f; lrow[qi][r] = 0.f; }

  for (int ti=0; ti<ntiles; ++ti){
    const int kv0 = kvbase + ti*64;
    s16x8 kfr[4][3];
#pragma unroll
    for (int cf=0;cf<4;++cf)
#pragma unroll
      for (int kf=0;kf<3;++kf)
        kfr[cf][kf] = *(const s16x8*)(Kbase + (long)(kv0+cf*16+col)*768 + kf*32 + g*8);
    f32x4 sc[2][4];
#pragma unroll
    for (int qi=0;qi<2;++qi)
#pragma unroll
      for (int cf=0;cf<4;++cf) sc[qi][cf] = fz;
#pragma unroll
    for (int kf=0;kf<3;++kf)
#pragma unroll
      for (int qi=0;qi<2;++qi)
#pragma unroll
        for (int cf=0;cf<4;++cf)
          sc[qi][cf] = mfma_bf16(qf[qi][kf], kfr[cf][kf], sc[qi][cf]);
    float bv[4];
#pragma unroll
    for (int cf=0;cf<4;++cf) bv[cf] = bb[kv0+cf*16+col];

#pragma unroll
    for (int qi=0;qi<2;++qi){
      f32x4 sp[4];
#pragma unroll
      for (int cf=0;cf<4;++cf)
#pragma unroll
        for (int r=0;r<4;++r) sp[cf][r] = sc[qi][cf][r]*scale + bv[cf];
      f32x4 mx = sp[0];
#pragma unroll
      for (int cf=1;cf<4;++cf)
#pragma unroll
        for (int r=0;r<4;++r) mx[r] = fmaxf(mx[r], sp[cf][r]);
      for (int mm=1;mm<16;mm<<=1){
#pragma unroll
        for (int r=0;r<4;++r) mx[r] = fmaxf(mx[r], __shfl_xor(mx[r], mm));
      }
      float sf[4], mn[4];
#pragma unroll
      for (int r=0;r<4;++r){
        mn[r] = fmaxf(mrow[qi][r], mx[r]);
        sf[r] = __expf(mrow[qi][r]-mn[r]);
        mrow[qi][r] = mn[r];
      }
      f32x4 psum = fz;
#pragma unroll
      for (int cf=0;cf<4;++cf)
#pragma unroll
        for (int r=0;r<4;++r){ float p = __expf(sp[cf][r]-mn[r]); sp[cf][r]=p; psum[r]+=p; }
      for (int mm=1;mm<16;mm<<=1){
#pragma unroll
        for (int r=0;r<4;++r) psum[r] += __shfl_xor(psum[r], mm);
      }
#pragma unroll
      for (int r=0;r<4;++r) lrow[qi][r] = lrow[qi][r]*sf[r] + psum[r];
#pragma unroll
      for (int nf=0;nf<6;++nf)
#pragma unroll
        for (int r=0;r<4;++r) of[qi][nf][r] *= sf[r];
      // store P tile (bf16) to swizzled LDS
#pragma unroll
      for (int cf=0;cf<4;++cf)
#pragma unroll
        for (int r=0;r<4;++r){
          int lr = qi*16 + g*4 + r;
          int cc = cf*16 + col;
          int byteoff = (qrow + lr)*128 + ((cc*2) ^ ((lr&7)<<4));
          *(u16*)((char*)Ps + byteoff) = f2bf(sp[cf][r]);
        }
    }
    // PV: O += P @ V  (all within the same wave; compiler orders LDS ops)
#pragma unroll
    for (int k2=0;k2<2;++k2){
      s16x8 pa[2];
#pragma unroll
      for (int qi=0;qi<2;++qi){
        int lr = qi*16 + col;
        int byteoff = (qrow+lr)*128 + ((k2*64 + g*16) ^ ((lr&7)<<4));
        pa[qi] = *(const s16x8*)((const char*)Ps + byteoff);
      }
#pragma unroll
      for (int nf=0;nf<6;++nf){
        s16x8 vbf = *(const s16x8*)(Vbase + (long)(nf*16+col)*HW + kv0 + k2*32 + g*8);
#pragma unroll
        for (int qi=0;qi<2;++qi)
          of[qi][nf] = mfma_bf16(pa[qi], vbf, of[qi][nf]);
      }
    }
  }
  long obase = ((long)ch*64 + bh)*128;
#pragma unroll
  for (int qi=0;qi<2;++qi)
#pragma unroll
    for (int nf=0;nf<6;++nf)
#pragma unroll
      for (int r=0;r<4;++r)
        Opart[(obase + qrow + qi*16 + g*4 + r)*96L + nf*16 + col] = of[qi][nf][r];
  if (col==0){
#pragma unroll
    for (int qi=0;qi<2;++qi)
#pragma unroll
      for (int r=0;r<4;++r){
        int row = qrow + qi*16 + g*4 + r;
        mpart[obase+row] = mrow[qi][r];
        lpart[obase+row] = lrow[qi][r];
      }
  }
}

__global__ __launch_bounds__(128) void attn_comb_k(const float* __restrict__ Opart,
    const float* __restrict__ mpart, const float* __restrict__ lpart,
    u16* __restrict__ out, int nch){
  int bh = blockIdx.x, q = blockIdx.y, d = threadIdx.x;
  int b = bh>>3, h = bh&7;
  float M = -1e30f;
  for (int c=0;c<nch;++c) M = fmaxf(M, mpart[((long)c*64+bh)*128+q]);
  float L = 0.f, o = 0.f;
  for (int c=0;c<nch;++c){
    long base = ((long)c*64+bh)*128+q;
    float e = __expf(mpart[base]-M);
    L += lpart[base]*e;
    if (d<96) o += Opart[base*96+d]*e;
  }
  if (d<96) out[((long)(b*100+q))*768 + h*96 + d] = f2bf(o/L);
}

// ---------------- residual + LN kernels (f32, wave per row) ----------------
__global__ __launch_bounds__(256) void postattn_k(const float* __restrict__ q,
    const float* __restrict__ fus, const float* __restrict__ g, const float* __restrict__ bt,
    float* __restrict__ x1f, u16* __restrict__ x1b){
  int w = threadIdx.x>>6, lane = threadIdx.x&63;
  long row = (long)blockIdx.x*4 + w;
  const f32x4* qp = (const f32x4*)(q   + row*768);
  const f32x4* fp = (const f32x4*)(fus + row*768);
  f32x4 xv[3];
  float s=0.f,s2=0.f;
#pragma unroll
  for (int p=0;p<3;++p){
    f32x4 a = qp[p*64+lane], c = fp[p*64+lane];
    xv[p] = a + c;
#pragma unroll
    for (int r=0;r<4;++r){ s += xv[p][r]; s2 += xv[p][r]*xv[p][r]; }
  }
  for (int m=1;m<64;m<<=1){ s += __shfl_xor(s,m); s2 += __shfl_xor(s2,m); }
  float mean = s*(1.f/768.f);
  float var  = s2*(1.f/768.f) - mean*mean;
  float rstd = rsqrtf(fmaxf(var,0.f)+1e-5f);
#pragma unroll
  for (int p=0;p<3;++p){
    int c0 = (p*64+lane)*4;
    f32x4 o; s16x4 ob;
#pragma unroll
    for (int r=0;r<4;++r){ o[r] = (xv[p][r]-mean)*rstd*g[c0+r]+bt[c0+r]; ob[r]=(short)f2bf(o[r]); }
    *(f32x4*)(x1f + row*768 + c0) = o;
    *(s16x4*)(x1b + row*768 + c0) = ob;
  }
}

__global__ __launch_bounds__(256) void final_k(const float* __restrict__ x1f,
    const float* __restrict__ yb, const float* __restrict__ g, const float* __restrict__ bt,
    float* __restrict__ out){
  int w = threadIdx.x>>6, lane = threadIdx.x&63;
  long row = (long)blockIdx.x*4 + w;
  const f32x4* xp = (const f32x4*)(x1f + row*768);
  const f32x4* yp = (const f32x4*)(yb  + row*768);
  f32x4 xv[3];
  float s=0.f,s2=0.f;
#pragma unroll
  for (int p=0;p<3;++p){
    f32x4 a = xp[p*64+lane], c = yp[p*64+lane];
    xv[p] = a + c;
#pragma unroll
    for (int r=0;r<4;++r){ s += xv[p][r]; s2 += xv[p][r]*xv[p][r]; }
  }
  for (int m=1;m<64;m<<=1){ s += __shfl_xor(s,m); s2 += __shfl_xor(s2,m); }
  float mean = s*(1.f/768.f);
  float var  = s2*(1.f/768.f) - mean*mean;
  float rstd = rsqrtf(fmaxf(var,0.f)+1e-5f);
#pragma unroll
  for (int p=0;p<3;++p){
    int c0 = (p*64+lane)*4;
    f32x4 o;
#pragma unroll
    for (int r=0;r<4;++r) o[r] = (xv[p][r]-mean)*rstd*g[c0+r]+bt[c0+r];
    *(f32x4*)(out + row*768 + c0) = o;
  }
}

// ---------------- launcher ----------------
extern "C" void kernel_launch(void* const* d_in, const int* in_sizes, int n_in,
                              void* d_out, int out_size, void* d_ws, size_t ws_size,
                              hipStream_t stream)
{
  (void)in_sizes; (void)n_in; (void)out_size; (void)ws_size;
  const float* query = (const float*)d_in[0];
  const float* imgf  = (const float*)d_in[1];
  const float* kpts  = (const float*)d_in[2];
  const float* nfg   = (const float*)d_in[3];
  const float* nfb   = (const float*)d_in[4];
  const float* dsw   = (const float*)d_in[5];
  const float* dsb   = (const float*)d_in[6];
  const float* qw    = (const float*)d_in[7];
  const float* qbv   = (const float*)d_in[8];
  const float* kw    = (const float*)d_in[9];
  const float* kbv   = (const float*)d_in[10];
  const float* vw    = (const float*)d_in[11];
  const float* vbv   = (const float*)d_in[12];
  const float* ow    = (const float*)d_in[13];
  const float* obv   = (const float*)d_in[14];
  const float* sw    = (const float*)d_in[15];
  const float* nag   = (const float*)d_in[16];
  const float* nab   = (const float*)d_in[17];
  const float* fw1   = (const float*)d_in[18];
  const float* fb1   = (const float*)d_in[19];
  const float* fw2   = (const float*)d_in[20];
  const float* fb2   = (const float*)d_in[21];
  const float* ngg   = (const float*)d_in[22];
  const float* ngb   = (const float*)d_in[23];
  float* out = (float*)d_out;

  char* ws = (char*)d_ws;
  size_t off = 0;
  auto carve = [&](size_t bytes)->char*{
    off = (off + 255) & ~(size_t)255;
    char* p = ws + off; off += bytes; return p;
  };
  float* w3     = (float*)carve(16);
  u16* wq_t     = (u16*)carve(3UL*768*768*2);
  u16* wk_t     = (u16*)carve(3UL*768*768*2);
  u16* wv_t     = (u16*)carve(3UL*768*768*2);
  u16* wo_t     = (u16*)carve(3UL*768*768*2);
  u16* wf1_t    = (u16*)carve(3072UL*768*2);
  u16* wf2_t    = (u16*)carve(768UL*3072*2);
  u16* wcv_t    = (u16*)carve(2UL*4*768*768*2);
  u16* qbf      = (u16*)carve(896UL*768*2);   // padded to 896 rows (A of M=800 GEMM)
  u16* Qpad     = (u16*)carve(8UL*128*768*2);
  u16* curr0    = (u16*)carve(8UL*4096*768*2);
  u16* curr1    = (u16*)carve(8UL*1024*768*2);
  u16* curr2    = (u16*)carve(8UL*256*768*2);
  u16* feat     = (u16*)carve(8UL*4096*768*2);
  u16* Kb       = (u16*)carve(8UL*4096*768*2);
  u16* Vt       = (u16*)carve(8UL*768*4096*2);
  float* biasb  = (float*)carve(8UL*4096*4);
  float* Opart  = (float*)carve(8UL*64*128*96*4);
  float* mpart  = (float*)carve(8UL*64*128*4);
  float* lpart  = (float*)carve(8UL*64*128*4);
  u16* attnO    = (u16*)carve(896UL*768*2);   // padded
  float* fusedb = (float*)carve(800UL*768*4);
  float* x1f    = (float*)carve(800UL*768*4);
  u16* x1b      = (u16*)carve(896UL*768*2);   // padded
  u16* hb       = (u16*)carve(896UL*3072*2);  // padded
  float* yb     = (float*)carve(800UL*768*4);

  hipMemsetAsync(Qpad, 0, 8UL*128*768*2, stream);
  smax3_k<<<1,64,0,stream>>>(sw, w3);
  cvt_k<<<600,256,0,stream>>>(query, qbf, 153600);
  tr_k<<<dim3(24,24,3),256,0,stream>>>(qw, wq_t, 768, 768);
  tr_k<<<dim3(24,24,3),256,0,stream>>>(kw, wk_t, 768, 768);
  tr_k<<<dim3(24,24,3),256,0,stream>>>(vw, wv_t, 768, 768);
  tr_k<<<dim3(24,24,3),256,0,stream>>>(ow, wo_t, 768, 768);
  tr_k<<<dim3(96,24,1),256,0,stream>>>(fw1, wf1_t, 768, 3072);
  tr_k<<<dim3(24,96,1),256,0,stream>>>(fw2, wf2_t, 3072, 768);
  convw_k<<<4608,256,0,stream>>>(dsw, wcv_t);
  tr_k<<<dim3(128,24,8),256,0,stream>>>(imgf, curr0, 768, 4096);

  const int HWs[3]    = {4096,1024,256};
  const int log2Ws[3] = {6,5,4};
  const int chunks[3] = {8,4,2};
  const float sig[3]  = {0.05f,0.15f,0.3f};
  u16* currp[3] = {curr0, curr1, curr2};

  for (int s=0;s<3;++s){
    int HW = HWs[s], W = 1<<log2Ws[s];
    int M = 8*HW;
    if (s>0){
      int HWin = HWs[s-1], Win = 1<<log2Ws[s-1];
      gemm_k<0,false,false,true><<<dim3(M/128,6),256,0,stream>>>(
        currp[s-1], wcv_t + (long)(s-1)*4*768*768, dsb + (s-1)*768, currp[s],
        M, 768, 768, nullptr, 0,
        Win, HWin, log2Ws[s], 2*log2Ws[s], 0);
    }
    ln_bf16_k<<<M/4,256,0,stream>>>(currp[s], feat, nfg, nfb, M);
    gemm_k<0,false,false,false><<<dim3(M/128,6),256,0,stream>>>(
      feat, wk_t + (long)s*768*768, kbv + s*768, Kb, M, 768, 768,
      nullptr, 0, 0,0,0,0,0);
    gemm_k<3,false,false,false><<<dim3(M/128,6),256,0,stream>>>(
      feat, wv_t + (long)s*768*768, vbv + s*768, Vt, M, 768, 768,
      nullptr, 0, 0,0,0, 2*log2Ws[s], HW);
    gemm_k<0,false,true,false><<<dim3(7,6),256,0,stream>>>(
      qbf, wq_t + (long)s*768*768, qbv + s*768, Qpad, 800, 768, 768,
      nullptr, 0, 0,0,0,0,0);
    float inv2s2 = 1.f/(2.f*sig[s]*sig[s]);
    float invWm1 = 1.f/(float)(W-1);
    bias_k<<<dim3(HW/256,8),256,0,stream>>>(kpts, biasb, HW, log2Ws[s], invWm1, invWm1, inv2s2);
    attn_fwd_k<<<dim3(64,chunks[s]),256,0,stream>>>(
      Qpad, Kb, Vt, biasb, Opart, mpart, lpart, HW, (HW/64)/chunks[s]);
    attn_comb_k<<<dim3(64,100),128,0,stream>>>(Opart, mpart, lpart, attnO, chunks[s]);
    gemm_k<2,false,false,false><<<dim3(7,6),256,0,stream>>>(
      attnO, wo_t + (long)s*768*768, obv + s*768, fusedb, 800, 768, 768,
      w3+s, (s==0)?1:0, 0,0,0,0,0);
  }

  postattn_k<<<200,256,0,stream>>>(query, fusedb, nag, nab, x1f, x1b);
  gemm_k<0,true,false,false><<<dim3(7,24),256,0,stream>>>(
    x1b, wf1_t, fb1, hb, 800, 3072, 768, nullptr, 0, 0,0,0,0,0);
  gemm_k<1,false,false,false><<<dim3(7,6),256,0,stream>>>(
    hb, wf2_t, fb2, yb, 800, 768, 3072, nullptr, 0, 0,0,0,0,0);
  final_k<<<200,256,0,stream>>>(x1f, yb, ngg, ngb, out);
}

// Round 9
// 1090.568 us; speedup vs baseline: 1.0429x; 1.0260x over previous
//
#include <hip/hip_runtime.h>
#include <stdint.h>

// PoseGuidedMultipoleFusion — MI355X bf16 MFMA implementation.
// B=8, NQ=100, C=768, H0=64, NH=8 (d=96), NS=3, HID=3072.
// R6: LDS XOR-swizzle -> bank conflicts 4.7M -> 0 (verified R7), but latency-bound.
// R7: double-buffered staging, issue-before-compute, 1 barrier/K-step (T3 2-phase),
//     launch_bounds(256,4). Targets the exposed vmcnt(0) drain (MfmaUtil 15%, Occ 16%).

typedef unsigned short u16;
typedef __attribute__((ext_vector_type(4))) float f32x4;
typedef __attribute__((ext_vector_type(8))) short s16x8;
typedef __attribute__((ext_vector_type(4))) short s16x4;

#define DEVI static __device__ __forceinline__

DEVI float bf2f(u16 u){ union { unsigned int ui; float f; } v; v.ui = ((unsigned int)u)<<16; return v.f; }
DEVI u16 f2bf(float f){ union { float f; unsigned int ui; } v; v.f = f;
  unsigned int r = v.ui + 0x7FFFu + ((v.ui>>16)&1u); return (u16)(r>>16); }
DEVI f32x4 mfma_bf16(s16x8 a, s16x8 b, f32x4 c){
  return __builtin_amdgcn_mfma_f32_16x16x32_bf16(a,b,c,0,0,0);
}
// async global->LDS, 16B per lane. LDS side must be linear (base + lane*16).
DEVI void gload_lds16(const void* g, void* l){
  __builtin_amdgcn_global_load_lds((const __attribute__((address_space(1))) void*)g,
                                   (__attribute__((address_space(3))) void*)l, 16, 0, 0);
}

// ---------------- small prep kernels ----------------

__global__ __launch_bounds__(64) void smax3_k(const float* __restrict__ sw, float* __restrict__ w3){
  if (threadIdx.x==0){
    float a=sw[0],b=sw[1],c=sw[2];
    float mx=fmaxf(a,fmaxf(b,c));
    float ea=__expf(a-mx), eb=__expf(b-mx), ec=__expf(c-mx);
    float inv=1.f/(ea+eb+ec);
    w3[0]=ea*inv; w3[1]=eb*inv; w3[2]=ec*inv;
  }
}

__global__ __launch_bounds__(256) void cvt_k(const float* __restrict__ in, u16* __restrict__ out, int n4){
  int i = blockIdx.x*256 + threadIdx.x;
  if (i>=n4) return;
  f32x4 v = *(const f32x4*)(in + (long)i*4);
  s16x4 o;
  o[0]=(short)f2bf(v[0]); o[1]=(short)f2bf(v[1]); o[2]=(short)f2bf(v[2]); o[3]=(short)f2bf(v[3]);
  *(s16x4*)(out + (long)i*4) = o;
}

// transpose f32 [z][R][C] -> bf16 [z][C][R]
__global__ __launch_bounds__(256) void tr_k(const float* __restrict__ in, u16* __restrict__ out, int R, int C){
  __shared__ float tile[32][33];
  long z = blockIdx.z;
  in  += z*(long)R*C;
  out += z*(long)R*C;
  int tx = threadIdx.x & 31, ty = threadIdx.x>>5;   // 32 x 8
  int r0 = blockIdx.y*32, c0 = blockIdx.x*32;
#pragma unroll
  for (int j=0;j<4;++j) tile[ty+j*8][tx] = in[(long)(r0+ty+j*8)*C + c0+tx];
  __syncthreads();
#pragma unroll
  for (int j=0;j<4;++j) out[(long)(c0+ty+j*8)*R + r0+tx] = f2bf(tile[tx][ty+j*8]);
}

// ds_w [2][O=768][I=768][dyx=4] f32  ->  wcv_t [2][4][O][I] bf16 (B' = W^T per shift)
__global__ __launch_bounds__(256) void convw_k(const float* __restrict__ dsw, u16* __restrict__ out){
  int i = blockIdx.x*256 + threadIdx.x;           // over 2*768*768
  f32x4 v = *(const f32x4*)(dsw + (long)i*4);
  int s = i/(768*768); int rem = i - s*768*768;
  int o = rem/768; int ii = rem - o*768;
#pragma unroll
  for (int dyx=0;dyx<4;++dyx)
    out[(((long)s*4+dyx)*768 + o)*768 + ii] = f2bf(v[dyx]);
}

// ---------------- LayerNorm over C=768 (bf16 in/out), one wave per row ----------------
__global__ __launch_bounds__(256) void ln_bf16_k(const u16* __restrict__ in, u16* __restrict__ out,
    const float* __restrict__ g, const float* __restrict__ bt, int nrows){
  int w = threadIdx.x>>6, lane = threadIdx.x&63;
  long row = (long)blockIdx.x*4 + w;
  if (row >= nrows) return;
  const u16* rp = in + row*768;
  s16x8 v8 = *(const s16x8*)(rp + lane*8);
  s16x4 v4 = *(const s16x4*)(rp + 512 + lane*4);
  float x[12];
#pragma unroll
  for (int i=0;i<8;++i) x[i]   = bf2f((u16)v8[i]);
#pragma unroll
  for (int i=0;i<4;++i) x[8+i] = bf2f((u16)v4[i]);
  float s=0.f,s2=0.f;
#pragma unroll
  for (int i=0;i<12;++i){ s += x[i]; s2 += x[i]*x[i]; }
  for (int m=1;m<64;m<<=1){ s += __shfl_xor(s,m); s2 += __shfl_xor(s2,m); }
  float mean = s*(1.f/768.f);
  float var  = s2*(1.f/768.f) - mean*mean;
  float rstd = rsqrtf(fmaxf(var,0.f)+1e-5f);
  u16* op = out + row*768;
  s16x8 o8; s16x4 o4;
#pragma unroll
  for (int i=0;i<8;++i){ int c = lane*8+i;     o8[i] = (short)f2bf((x[i]-mean)*rstd*g[c]+bt[c]); }
#pragma unroll
  for (int i=0;i<4;++i){ int c = 512+lane*4+i; o4[i] = (short)f2bf((x[8+i]-mean)*rstd*g[c]+bt[c]); }
  *(s16x8*)(op + lane*8) = o8;
  *(s16x4*)(op + 512 + lane*4) = o4;
}

// ---------------- keypoint distance bias ----------------
__global__ __launch_bounds__(256) void bias_k(const float* __restrict__ kpts, float* __restrict__ out,
    int HW, int log2W, float invWm1, float invHm1, float inv2s2){
  __shared__ float2 kp[17];
  int b = blockIdx.y;
  if (threadIdx.x < 17) kp[threadIdx.x] = ((const float2*)kpts)[b*17 + threadIdx.x];
  __syncthreads();
  int p = blockIdx.x*256 + threadIdx.x;
  int W = 1<<log2W;
  int y = p>>log2W, x = p&(W-1);
  float gx = x*invWm1, gy = y*invHm1;
  float m = 1e30f;
#pragma unroll 1
  for (int k=0;k<17;++k){
    float kx = fminf(fmaxf(kp[k].x,0.f),1.f) - gx;
    float ky = fminf(fmaxf(kp[k].y,0.f),1.f) - gy;
    m = fminf(m, kx*kx+ky*ky);
  }
  out[(long)b*HW + p] = fmaxf(-m*inv2s2, -10000.f);
}

// ---------------- generic bf16 MFMA GEMM (double-buffered, 2-phase) ----------------
// C[M,N] = A[M,K] @ B'[N,K]^T (+bias). OUTM: 0 bf16, 1 f32, 2 f32 accumulate alpha, 3 bf16 transposed (V^T).
// QPAD: out row remap r -> (r/100)*128 + r%100.  CONV: A-row remap + 4 dyx shifts of B'.
// NOTE: A must be readable for ceil(M/128)*128 rows (pad buffers); epilogue guards row<M.
// LDS swizzle (R6, verified): physical 16B-block (r,cv) holds logical cv^((r>>1)&3), applied
// on the GLOBAL source; inverted on ds_read -> 2-way bank aliasing (free).
// Pipeline (R7): stage tile t+1 into buf^1 BEFORE computing tile t from buf; one
// __syncthreads per step (its vmcnt(0) drain overlaps with this step's compute).
template<int OUTM, bool RELU, bool QPAD, bool CONV>
__global__ __launch_bounds__(256,4) void gemm_k(
    const u16* __restrict__ A, const u16* __restrict__ Bt,
    const float* __restrict__ bias, void* __restrict__ Cout,
    int M, int N, int K,
    const float* __restrict__ alpha_ptr, int accum_init,
    int Win, int HWin, int log2Wout, int log2HWout, int ldct)
{
  __shared__ u16 As[2][128*32];
  __shared__ u16 Bs[2][128*32];
  const int t = threadIdx.x, lane = t&63, w = t>>6;
  const int wr = w>>1, wc = w&1;
  const int m0 = blockIdx.x*128, n0 = blockIdx.y*128;
  f32x4 acc[4][4];
  const f32x4 fz = {0.f,0.f,0.f,0.f};
#pragma unroll
  for (int i=0;i<4;++i)
#pragma unroll
    for (int j=0;j<4;++j) acc[i][j] = fz;

  const int nk = K>>5;
  const int nt = (CONV ? 4*nk : nk);

  auto stage = [&](int dyx, int k0, int b){
    const u16* Bp = CONV ? (Bt + (long)dyx*N*K) : Bt;
    const int dy = dyx>>1, dx = dyx&1;
#pragma unroll
    for (int p=0;p<2;++p){
      int f = p*256+t, r = f>>2, cv = f&3;
      int cvs = cv ^ ((r>>1)&3);            // pre-swizzled global k-block
      int gm = m0 + r;
      long arow;
      if (CONV){
        int bb = gm >> log2HWout;
        int pp = gm & ((1<<log2HWout)-1);
        int yy = pp >> log2Wout, xx = pp & ((1<<log2Wout)-1);
        arow = (long)bb*HWin + (2*yy+dy)*Win + (2*xx+dx);
      } else arow = gm;
      gload_lds16(A + arow*(long)K + k0 + cvs*8, &As[b][(long)f*8]);
    }
#pragma unroll
    for (int p=0;p<2;++p){
      int f = p*256+t, r = f>>2, cv = f&3;
      int cvs = cv ^ ((r>>1)&3);
      gload_lds16(Bp + (long)(n0+r)*K + k0 + cvs*8, &Bs[b][(long)f*8]);
    }
  };

  stage(0, 0, 0);
  __syncthreads();                          // drains vmcnt(0) before barrier

  int cur = 0, dyx = 0, kk = 0;
  for (int s = 0; s < nt; ++s){
    // next-step coordinates
    int nkk = kk + 1, ndx = dyx;
    if (nkk == nk){ nkk = 0; ndx = dyx + 1; }
    if (s + 1 < nt) stage(ndx, nkk<<5, cur^1);   // issue loads for t+1 (latency hides under compute)

    const int g16 = lane>>4, l16 = lane&15;
    s16x8 af[4], bf[4];
#pragma unroll
    for (int i=0;i<4;++i){
      int row = wr*64 + i*16 + l16;
      af[i] = *(const s16x8*)&As[cur][row*32 + ((g16 ^ ((row>>1)&3))*8)];
    }
#pragma unroll
    for (int j=0;j<4;++j){
      int row = wc*64 + j*16 + l16;
      bf[j] = *(const s16x8*)&Bs[cur][row*32 + ((g16 ^ ((row>>1)&3))*8)];
    }
#pragma unroll
    for (int i=0;i<4;++i)
#pragma unroll
      for (int j=0;j<4;++j)
        acc[i][j] = mfma_bf16(af[i], bf[j], acc[i][j]);

    __syncthreads();                        // drain t+1 loads + cross-wave visibility
    cur ^= 1; kk = nkk; dyx = ndx;
  }

  // epilogue: C/D layout col=lane&15, row=(lane>>4)*4+r
  const int col16 = lane&15, g = lane>>4;
  float alpha = (OUTM==2) ? *alpha_ptr : 1.f;
#pragma unroll
  for (int i=0;i<4;++i){
    int rowbase = m0 + wr*64 + i*16 + g*4;
#pragma unroll
    for (int j=0;j<4;++j){
      int colg = n0 + wc*64 + j*16 + col16;
      float bv = bias ? bias[colg] : 0.f;
      f32x4 c = acc[i][j];
      if (OUTM==3){
        if (rowbase < M){
          int bb  = rowbase >> log2HWout;
          int pix = rowbase & ((1<<log2HWout)-1);
          s16x4 pk;
          pk[0]=(short)f2bf(c[0]+bv); pk[1]=(short)f2bf(c[1]+bv);
          pk[2]=(short)f2bf(c[2]+bv); pk[3]=(short)f2bf(c[3]+bv);
          *(s16x4*)((u16*)Cout + ((long)bb*768 + colg)*ldct + pix) = pk;
        }
      } else {
#pragma unroll
        for (int r=0;r<4;++r){
          int row = rowbase + r;
          if (row < M){
            float v = c[r] + bv;
            if (RELU) v = fmaxf(v, 0.f);
            if (OUTM==0){
              long orow = row;
              if (QPAD){ int bb = row/100; orow = bb*128 + (row - bb*100); }
              ((u16*)Cout)[orow*(long)N + colg] = f2bf(v);
            } else if (OUTM==1){
              ((float*)Cout)[(long)row*N + colg] = v;
            } else {
              float* p = (float*)Cout + (long)row*N + colg;
              *p = (accum_init ? 0.f : *p) + alpha*v;
            }
          }
        }
      }
    }
  }
}

// ---------------- flash attention, k-chunked ----------------
// Qp [B][128][768] bf16 (rows>=100 zero), Kb [B][HW][768] bf16, Vt [B][768][HW] bf16, biasb [B][HW] f32.
// Opart [nch][64][128][96] f32 (unnormalized), mpart/lpart [nch][64][128].
__global__ __launch_bounds__(256,2) void attn_fwd_k(
    const u16* __restrict__ Qp, const u16* __restrict__ Kb,
    const u16* __restrict__ Vt, const float* __restrict__ biasb,
    float* __restrict__ Opart, float* __restrict__ mpart, float* __restrict__ lpart,
    int HW, int ntiles)
{
  __shared__ u16 Ps[4*32*64];   // per-wave 32x64 bf16, XOR-swizzled
  const int t = threadIdx.x, lane = t&63, w = t>>6;
  const int col = lane&15, g = lane>>4;
  const int bh = blockIdx.x, b = bh>>3, h = bh&7, ch = blockIdx.y;
  const int kvbase = ch*ntiles*64;
  const int qrow = w*32;
  const u16* Qbase = Qp + (long)b*128*768 + h*96;
  const u16* Kbase = Kb + (long)b*HW*768 + h*96;
  const u16* Vbase = Vt + ((long)b*768 + h*96)*HW;
  const float* bb  = biasb + (long)b*HW;
  const float scale = 0.10206207261596575f;  // 96^-0.5

  s16x8 qf[2][3];
#pragma unroll
  for (int qi=0;qi<2;++qi)
#pragma unroll
    for (int kf=0;kf<3;++kf)
      qf[qi][kf] = *(const s16x8*)(Qbase + (long)(qrow+qi*16+col)*768 + kf*32 + g*8);

  const f32x4 fz = {0.f,0.f,0.f,0.f};
  f32x4 of[2][6];
#pragma unroll
  for (int qi=0;qi<2;++qi)
#pragma unroll
    for (int nf=0;nf<6;++nf) of[qi][nf] = fz;
  float mrow[2][4], lrow[2][4];
#pragma unroll
  for (int qi=0;qi<2;++qi)
#pragma unroll
    for (int r=0;r<4;++r){ mrow[qi][r] = -1e30f; lrow[qi][r] = 0.f; }

  for (int ti=0; ti<ntiles; ++ti){
    const int kv0 = kvbase + ti*64;
    s16x8 kfr[4][3];
#pragma unroll
    for (int cf=0;cf<4;++cf)
#pragma unroll
      for (int kf=0;kf<3;++kf)
        kfr[cf][kf] = *(const s16x8*)(Kbase + (long)(kv0+cf*16+col)*768 + kf*32 + g*8);
    f32x4 sc[2][4];
#pragma unroll
    for (int qi=0;qi<2;++qi)
#pragma unroll
      for (int cf=0;cf<4;++cf) sc[qi][cf] = fz;
#pragma unroll
    for (int kf=0;kf<3;++kf)
#pragma unroll
      for (int qi=0;qi<2;++qi)
#pragma unroll
        for (int cf=0;cf<4;++cf)
          sc[qi][cf] = mfma_bf16(qf[qi][kf], kfr[cf][kf], sc[qi][cf]);
    float bv[4];
#pragma unroll
    for (int cf=0;cf<4;++cf) bv[cf] = bb[kv0+cf*16+col];

#pragma unroll
    for (int qi=0;qi<2;++qi){
      f32x4 sp[4];
#pragma unroll
      for (int cf=0;cf<4;++cf)
#pragma unroll
        for (int r=0;r<4;++r) sp[cf][r] = sc[qi][cf][r]*scale + bv[cf];
      f32x4 mx = sp[0];
#pragma unroll
      for (int cf=1;cf<4;++cf)
#pragma unroll
        for (int r=0;r<4;++r) mx[r] = fmaxf(mx[r], sp[cf][r]);
      for (int mm=1;mm<16;mm<<=1){
#pragma unroll
        for (int r=0;r<4;++r) mx[r] = fmaxf(mx[r], __shfl_xor(mx[r], mm));
      }
      float sf[4], mn[4];
#pragma unroll
      for (int r=0;r<4;++r){
        mn[r] = fmaxf(mrow[qi][r], mx[r]);
        sf[r] = __expf(mrow[qi][r]-mn[r]);
        mrow[qi][r] = mn[r];
      }
      f32x4 psum = fz;
#pragma unroll
      for (int cf=0;cf<4;++cf)
#pragma unroll
        for (int r=0;r<4;++r){ float p = __expf(sp[cf][r]-mn[r]); sp[cf][r]=p; psum[r]+=p; }
      for (int mm=1;mm<16;mm<<=1){
#pragma unroll
        for (int r=0;r<4;++r) psum[r] += __shfl_xor(psum[r], mm);
      }
#pragma unroll
      for (int r=0;r<4;++r) lrow[qi][r] = lrow[qi][r]*sf[r] + psum[r];
#pragma unroll
      for (int nf=0;nf<6;++nf)
#pragma unroll
        for (int r=0;r<4;++r) of[qi][nf][r] *= sf[r];
      // store P tile (bf16) to swizzled LDS
#pragma unroll
      for (int cf=0;cf<4;++cf)
#pragma unroll
        for (int r=0;r<4;++r){
          int lr = qi*16 + g*4 + r;
          int cc = cf*16 + col;
          int byteoff = (qrow + lr)*128 + ((cc*2) ^ ((lr&7)<<4));
          *(u16*)((char*)Ps + byteoff) = f2bf(sp[cf][r]);
        }
    }
    // PV: O += P @ V  (all within the same wave; compiler orders LDS ops)
#pragma unroll
    for (int k2=0;k2<2;++k2){
      s16x8 pa[2];
#pragma unroll
      for (int qi=0;qi<2;++qi){
        int lr = qi*16 + col;
        int byteoff = (qrow+lr)*128 + ((k2*64 + g*16) ^ ((lr&7)<<4));
        pa[qi] = *(const s16x8*)((const char*)Ps + byteoff);
      }
#pragma unroll
      for (int nf=0;nf<6;++nf){
        s16x8 vbf = *(const s16x8*)(Vbase + (long)(nf*16+col)*HW + kv0 + k2*32 + g*8);
#pragma unroll
        for (int qi=0;qi<2;++qi)
          of[qi][nf] = mfma_bf16(pa[qi], vbf, of[qi][nf]);
      }
    }
  }
  long obase = ((long)ch*64 + bh)*128;
#pragma unroll
  for (int qi=0;qi<2;++qi)
#pragma unroll
    for (int nf=0;nf<6;++nf)
#pragma unroll
      for (int r=0;r<4;++r)
        Opart[(obase + qrow + qi*16 + g*4 + r)*96L + nf*16 + col] = of[qi][nf][r];
  if (col==0){
#pragma unroll
    for (int qi=0;qi<2;++qi)
#pragma unroll
      for (int r=0;r<4;++r){
        int row = qrow + qi*16 + g*4 + r;
        mpart[obase+row] = mrow[qi][r];
        lpart[obase+row] = lrow[qi][r];
      }
  }
}

__global__ __launch_bounds__(128) void attn_comb_k(const float* __restrict__ Opart,
    const float* __restrict__ mpart, const float* __restrict__ lpart,
    u16* __restrict__ out, int nch){
  int bh = blockIdx.x, q = blockIdx.y, d = threadIdx.x;
  int b = bh>>3, h = bh&7;
  float M = -1e30f;
  for (int c=0;c<nch;++c) M = fmaxf(M, mpart[((long)c*64+bh)*128+q]);
  float L = 0.f, o = 0.f;
  for (int c=0;c<nch;++c){
    long base = ((long)c*64+bh)*128+q;
    float e = __expf(mpart[base]-M);
    L += lpart[base]*e;
    if (d<96) o += Opart[base*96+d]*e;
  }
  if (d<96) out[((long)(b*100+q))*768 + h*96 + d] = f2bf(o/L);
}

// ---------------- residual + LN kernels (f32, wave per row) ----------------
__global__ __launch_bounds__(256) void postattn_k(const float* __restrict__ q,
    const float* __restrict__ fus, const float* __restrict__ g, const float* __restrict__ bt,
    float* __restrict__ x1f, u16* __restrict__ x1b){
  int w = threadIdx.x>>6, lane = threadIdx.x&63;
  long row = (long)blockIdx.x*4 + w;
  const f32x4* qp = (const f32x4*)(q   + row*768);
  const f32x4* fp = (const f32x4*)(fus + row*768);
  f32x4 xv[3];
  float s=0.f,s2=0.f;
#pragma unroll
  for (int p=0;p<3;++p){
    f32x4 a = qp[p*64+lane], c = fp[p*64+lane];
    xv[p] = a + c;
#pragma unroll
    for (int r=0;r<4;++r){ s += xv[p][r]; s2 += xv[p][r]*xv[p][r]; }
  }
  for (int m=1;m<64;m<<=1){ s += __shfl_xor(s,m); s2 += __shfl_xor(s2,m); }
  float mean = s*(1.f/768.f);
  float var  = s2*(1.f/768.f) - mean*mean;
  float rstd = rsqrtf(fmaxf(var,0.f)+1e-5f);
#pragma unroll
  for (int p=0;p<3;++p){
    int c0 = (p*64+lane)*4;
    f32x4 o; s16x4 ob;
#pragma unroll
    for (int r=0;r<4;++r){ o[r] = (xv[p][r]-mean)*rstd*g[c0+r]+bt[c0+r]; ob[r]=(short)f2bf(o[r]); }
    *(f32x4*)(x1f + row*768 + c0) = o;
    *(s16x4*)(x1b + row*768 + c0) = ob;
  }
}

__global__ __launch_bounds__(256) void final_k(const float* __restrict__ x1f,
    const float* __restrict__ yb, const float* __restrict__ g, const float* __restrict__ bt,
    float* __restrict__ out){
  int w = threadIdx.x>>6, lane = threadIdx.x&63;
  long row = (long)blockIdx.x*4 + w;
  const f32x4* xp = (const f32x4*)(x1f + row*768);
  const f32x4* yp = (const f32x4*)(yb  + row*768);
  f32x4 xv[3];
  float s=0.f,s2=0.f;
#pragma unroll
  for (int p=0;p<3;++p){
    f32x4 a = xp[p*64+lane], c = yp[p*64+lane];
    xv[p] = a + c;
#pragma unroll
    for (int r=0;r<4;++r){ s += xv[p][r]; s2 += xv[p][r]*xv[p][r]; }
  }
  for (int m=1;m<64;m<<=1){ s += __shfl_xor(s,m); s2 += __shfl_xor(s2,m); }
  float mean = s*(1.f/768.f);
  float var  = s2*(1.f/768.f) - mean*mean;
  float rstd = rsqrtf(fmaxf(var,0.f)+1e-5f);
#pragma unroll
  for (int p=0;p<3;++p){
    int c0 = (p*64+lane)*4;
    f32x4 o;
#pragma unroll
    for (int r=0;r<4;++r) o[r] = (xv[p][r]-mean)*rstd*g[c0+r]+bt[c0+r];
    *(f32x4*)(out + row*768 + c0) = o;
  }
}

// ---------------- launcher ----------------
extern "C" void kernel_launch(void* const* d_in, const int* in_sizes, int n_in,
                              void* d_out, int out_size, void* d_ws, size_t ws_size,
                              hipStream_t stream)
{
  (void)in_sizes; (void)n_in; (void)out_size; (void)ws_size;
  const float* query = (const float*)d_in[0];
  const float* imgf  = (const float*)d_in[1];
  const float* kpts  = (const float*)d_in[2];
  const float* nfg   = (const float*)d_in[3];
  const float* nfb   = (const float*)d_in[4];
  const float* dsw   = (const float*)d_in[5];
  const float* dsb   = (const float*)d_in[6];
  const float* qw    = (const float*)d_in[7];
  const float* qbv   = (const float*)d_in[8];
  const float* kw    = (const float*)d_in[9];
  const float* kbv   = (const float*)d_in[10];
  const float* vw    = (const float*)d_in[11];
  const float* vbv   = (const float*)d_in[12];
  const float* ow    = (const float*)d_in[13];
  const float* obv   = (const float*)d_in[14];
  const float* sw    = (const float*)d_in[15];
  const float* nag   = (const float*)d_in[16];
  const float* nab   = (const float*)d_in[17];
  const float* fw1   = (const float*)d_in[18];
  const float* fb1   = (const float*)d_in[19];
  const float* fw2   = (const float*)d_in[20];
  const float* fb2   = (const float*)d_in[21];
  const float* ngg   = (const float*)d_in[22];
  const float* ngb   = (const float*)d_in[23];
  float* out = (float*)d_out;

  char* ws = (char*)d_ws;
  size_t off = 0;
  auto carve = [&](size_t bytes)->char*{
    off = (off + 255) & ~(size_t)255;
    char* p = ws + off; off += bytes; return p;
  };
  float* w3     = (float*)carve(16);
  u16* wq_t     = (u16*)carve(3UL*768*768*2);
  u16* wk_t     = (u16*)carve(3UL*768*768*2);
  u16* wv_t     = (u16*)carve(3UL*768*768*2);
  u16* wo_t     = (u16*)carve(3UL*768*768*2);
  u16* wf1_t    = (u16*)carve(3072UL*768*2);
  u16* wf2_t    = (u16*)carve(768UL*3072*2);
  u16* wcv_t    = (u16*)carve(2UL*4*768*768*2);
  u16* qbf      = (u16*)carve(896UL*768*2);   // padded to 896 rows (A of M=800 GEMM)
  u16* Qpad     = (u16*)carve(8UL*128*768*2);
  u16* curr0    = (u16*)carve(8UL*4096*768*2);
  u16* curr1    = (u16*)carve(8UL*1024*768*2);
  u16* curr2    = (u16*)carve(8UL*256*768*2);
  u16* feat     = (u16*)carve(8UL*4096*768*2);
  u16* Kb       = (u16*)carve(8UL*4096*768*2);
  u16* Vt       = (u16*)carve(8UL*768*4096*2);
  float* biasb  = (float*)carve(8UL*4096*4);
  float* Opart  = (float*)carve(8UL*64*128*96*4);
  float* mpart  = (float*)carve(8UL*64*128*4);
  float* lpart  = (float*)carve(8UL*64*128*4);
  u16* attnO    = (u16*)carve(896UL*768*2);   // padded
  float* fusedb = (float*)carve(800UL*768*4);
  float* x1f    = (float*)carve(800UL*768*4);
  u16* x1b      = (u16*)carve(896UL*768*2);   // padded
  u16* hb       = (u16*)carve(896UL*3072*2);  // padded
  float* yb     = (float*)carve(800UL*768*4);

  hipMemsetAsync(Qpad, 0, 8UL*128*768*2, stream);
  smax3_k<<<1,64,0,stream>>>(sw, w3);
  cvt_k<<<600,256,0,stream>>>(query, qbf, 153600);
  tr_k<<<dim3(24,24,3),256,0,stream>>>(qw, wq_t, 768, 768);
  tr_k<<<dim3(24,24,3),256,0,stream>>>(kw, wk_t, 768, 768);
  tr_k<<<dim3(24,24,3),256,0,stream>>>(vw, wv_t, 768, 768);
  tr_k<<<dim3(24,24,3),256,0,stream>>>(ow, wo_t, 768, 768);
  tr_k<<<dim3(96,24,1),256,0,stream>>>(fw1, wf1_t, 768, 3072);
  tr_k<<<dim3(24,96,1),256,0,stream>>>(fw2, wf2_t, 3072, 768);
  convw_k<<<4608,256,0,stream>>>(dsw, wcv_t);
  tr_k<<<dim3(128,24,8),256,0,stream>>>(imgf, curr0, 768, 4096);

  const int HWs[3]    = {4096,1024,256};
  const int log2Ws[3] = {6,5,4};
  const int chunks[3] = {8,4,2};
  const float sig[3]  = {0.05f,0.15f,0.3f};
  u16* currp[3] = {curr0, curr1, curr2};

  for (int s=0;s<3;++s){
    int HW = HWs[s], W = 1<<log2Ws[s];
    int M = 8*HW;
    if (s>0){
      int HWin = HWs[s-1], Win = 1<<log2Ws[s-1];
      gemm_k<0,false,false,true><<<dim3(M/128,6),256,0,stream>>>(
        currp[s-1], wcv_t + (long)(s-1)*4*768*768, dsb + (s-1)*768, currp[s],
        M, 768, 768, nullptr, 0,
        Win, HWin, log2Ws[s], 2*log2Ws[s], 0);
    }
    ln_bf16_k<<<M/4,256,0,stream>>>(currp[s], feat, nfg, nfb, M);
    gemm_k<0,false,false,false><<<dim3(M/128,6),256,0,stream>>>(
      feat, wk_t + (long)s*768*768, kbv + s*768, Kb, M, 768, 768,
      nullptr, 0, 0,0,0,0,0);
    gemm_k<3,false,false,false><<<dim3(M/128,6),256,0,stream>>>(
      feat, wv_t + (long)s*768*768, vbv + s*768, Vt, M, 768, 768,
      nullptr, 0, 0,0,0, 2*log2Ws[s], HW);
    gemm_k<0,false,true,false><<<dim3(7,6),256,0,stream>>>(
      qbf, wq_t + (long)s*768*768, qbv + s*768, Qpad, 800, 768, 768,
      nullptr, 0, 0,0,0,0,0);
    float inv2s2 = 1.f/(2.f*sig[s]*sig[s]);
    float invWm1 = 1.f/(float)(W-1);
    bias_k<<<dim3(HW/256,8),256,0,stream>>>(kpts, biasb, HW, log2Ws[s], invWm1, invWm1, inv2s2);
    attn_fwd_k<<<dim3(64,chunks[s]),256,0,stream>>>(
      Qpad, Kb, Vt, biasb, Opart, mpart, lpart, HW, (HW/64)/chunks[s]);
    attn_comb_k<<<dim3(64,100),128,0,stream>>>(Opart, mpart, lpart, attnO, chunks[s]);
    gemm_k<2,false,false,false><<<dim3(7,6),256,0,stream>>>(
      attnO, wo_t + (long)s*768*768, obv + s*768, fusedb, 800, 768, 768,
      w3+s, (s==0)?1:0, 0,0,0,0,0);
  }

  postattn_k<<<200,256,0,stream>>>(query, fusedb, nag, nab, x1f, x1b);
  gemm_k<0,true,false,false><<<dim3(7,24),256,0,stream>>>(
    x1b, wf1_t, fb1, hb, 800, 3072, 768, nullptr, 0, 0,0,0,0,0);
  gemm_k<1,false,false,false><<<dim3(7,6),256,0,stream>>>(
    hb, wf2_t, fb2, yb, 800, 768, 3072, nullptr, 0, 0,0,0,0,0);
  final_k<<<200,256,0,stream>>>(x1f, yb, ngg, ngb, out);
}